// Round 7
// baseline (162.489 us; speedup 1.0000x reference)
//
#include <hip/hip_runtime.h>
#include <hip/hip_bf16.h>

typedef __hip_bfloat16 bf16;
typedef __bf16 bf16x8_t __attribute__((ext_vector_type(8)));
typedef float f32x4_t __attribute__((ext_vector_type(4)));
typedef float f32x16_t __attribute__((ext_vector_type(16)));

#define MFMA16(a, b, c) __builtin_amdgcn_mfma_f32_16x16x32_bf16(a, b, c, 0, 0, 0)
#define MFMA32(a, b, c) __builtin_amdgcn_mfma_f32_32x32x16_bf16(a, b, c, 0, 0, 0)

// global -> LDS direct copy, 16B per lane. LDS dest = wave-uniform chunk base
// (HW adds lane*16); global src is per-lane (so we pre-permute the source).
__device__ __forceinline__ void glds16(const void* g, void* l) {
    auto gp = (const __attribute__((address_space(1))) unsigned int*)(unsigned long long)(g);
    auto lp = (__attribute__((address_space(3))) unsigned int*)(unsigned int)(unsigned long long)(l);
    __builtin_amdgcn_global_load_lds(gp, lp, 16, 0, 0);
}

// R4-verified pack: lo16 = bf16(a), hi16 = bf16(b)
__device__ __forceinline__ unsigned pkbf16(float a, float b) {
    union { bf16 h; unsigned short u; } x, y;
    x.h = __float2bfloat16(a);
    y.h = __float2bfloat16(b);
    return ((unsigned)y.u << 16) | x.u;
}

// v_permlane32_swap_b32: a' = [a.lo32 | b.lo32], b' = [a.hi32 | b.hi32]
__device__ __forceinline__ void perm32swap(unsigned& a, unsigned& b) {
    asm volatile("v_permlane32_swap_b32 %0, %1" : "+v"(a), "+v"(b));
}

__device__ __forceinline__ float max3f(float a, float b, float c) {
    return fmaxf(fmaxf(a, b), c);  // clang fuses to v_max3_f32
}

// ---------------------------------------------------------------- conversions
__global__ void cvt_f32_bf16(const float* __restrict__ in, bf16* __restrict__ out, int n4) {
    int i = blockIdx.x * blockDim.x + threadIdx.x;
    if (i >= n4) return;
    const float4 v = reinterpret_cast<const float4*>(in)[i];
    bf16 o[4] = {__float2bfloat16(v.x), __float2bfloat16(v.y),
                 __float2bfloat16(v.z), __float2bfloat16(v.w)};
    *reinterpret_cast<ulonglong1*>(out + i * 4) = *reinterpret_cast<ulonglong1*>(o);
}

// in [R][C] f32  ->  out [C][R] bf16   (block (32,8), tile 32x32)
__global__ void transpose_cvt(const float* __restrict__ in, bf16* __restrict__ out, int R, int C) {
    __shared__ bf16 tile[32][33];
    const int c0 = blockIdx.x * 32, r0 = blockIdx.y * 32;
    const int tx = threadIdx.x, ty = threadIdx.y;
#pragma unroll
    for (int i = 0; i < 4; ++i) {
        int r = r0 + ty + i * 8;
        tile[ty + i * 8][tx] = __float2bfloat16(in[(size_t)r * C + c0 + tx]);
    }
    __syncthreads();
#pragma unroll
    for (int i = 0; i < 4; ++i) {
        int c = c0 + ty + i * 8;
        out[(size_t)c * R + r0 + tx] = tile[tx][ty + i * 8];
    }
}

// ---------------------------------------------------------------- GEMM
// C[M,N] = A[M,K] @ Bt[N,K]^T + bias.  BM=BN=128, BK=32, 256 thr (4 waves 2x2).
// FOUR LDS buffers, prefetch depth 2, ONE barrier per K-step:
//   stage(t+2) -> vmcnt(8) -> barrier -> compute(t&3)
// Race-free: writer of buf[t&3] is stage(t+4), issued at iter t+2 AFTER
// barrier(t+1), which guarantees all waves finished compute(t) (distance 3 < 4).
// MODE 0: QKV epilogue -> Q[B,H,L,64] (x 0.125*log2e, exp2 softmax), K, Vt.
// MODE 1: f32 out + bias
template <int MODE>
__global__ __launch_bounds__(256) void gemm_kernel(
    const bf16* __restrict__ A, const bf16* __restrict__ Bt, const float* __restrict__ bias,
    bf16* __restrict__ Qo, bf16* __restrict__ Ko, bf16* __restrict__ Vto,
    float* __restrict__ Fo, int N, int K) {
    __shared__ bf16 As[4][128 * 32];
    __shared__ bf16 Bs[4][128 * 32];
    const int tid = threadIdx.x, wid = tid >> 6, lane = tid & 63;
    const int lo = lane & 15, hi = lane >> 4;
    // XCD-aware swizzle (grid counts divisible by 8)
    const int nbx = gridDim.x;
    const int bid = blockIdx.x + nbx * blockIdx.y;
    const int chunk = (nbx * gridDim.y) >> 3;
    const int sb = (bid & 7) * chunk + (bid >> 3);
    const int bm = (sb % nbx) * 128, bn = (sb / nbx) * 128;
    const int wr = (wid >> 1) * 64, wc = (wid & 1) * 64;

    f32x4_t acc[4][4];
#pragma unroll
    for (int i = 0; i < 4; ++i)
#pragma unroll
        for (int j = 0; j < 4; ++j) acc[i][j] = (f32x4_t){0.f, 0.f, 0.f, 0.f};

    // per-lane staging source offsets
    const int g0 = wid * 2, g1 = wid * 2 + 1;
    const int r0 = (g0 * 1024 + lane * 16) >> 6, k0off = ((g0 * 1024 + lane * 16) & 63) >> 1;
    const int r1 = (g1 * 1024 + lane * 16) >> 6, k1off = ((g1 * 1024 + lane * 16) & 63) >> 1;

    auto STAGE = [&](int buf, int t) {
        const int kk = t * 32;
        glds16(A + (size_t)(bm + r0) * K + kk + k0off, (char*)&As[0][0] + buf * 8192 + g0 * 1024);
        glds16(Bt + (size_t)(bn + r0) * K + kk + k0off, (char*)&Bs[0][0] + buf * 8192 + g0 * 1024);
        glds16(A + (size_t)(bm + r1) * K + kk + k1off, (char*)&As[0][0] + buf * 8192 + g1 * 1024);
        glds16(Bt + (size_t)(bn + r1) * K + kk + k1off, (char*)&Bs[0][0] + buf * 8192 + g1 * 1024);
    };

    auto COMPUTE = [&](int buf) {
        const char* ab = (const char*)&As[0][0] + buf * 8192;
        const char* bb = (const char*)&Bs[0][0] + buf * 8192;
        bf16x8_t af[4], bfv[4];
#pragma unroll
        for (int i = 0; i < 4; ++i)
            af[i] = *(const bf16x8_t*)(ab + (wr + i * 16 + lo) * 64 + hi * 16);
#pragma unroll
        for (int j = 0; j < 4; ++j)
            bfv[j] = *(const bf16x8_t*)(bb + (wc + j * 16 + lo) * 64 + hi * 16);
        __builtin_amdgcn_s_setprio(1);
#pragma unroll
        for (int i = 0; i < 4; ++i)
#pragma unroll
            for (int j = 0; j < 4; ++j) acc[i][j] = MFMA16(af[i], bfv[j], acc[i][j]);
        __builtin_amdgcn_s_setprio(0);
    };

    const int nt = K >> 5;  // 32
    STAGE(0, 0);
    STAGE(1, 1);
    for (int t = 0; t < nt - 2; ++t) {
        STAGE((t + 2) & 3, t + 2);
        asm volatile("s_waitcnt vmcnt(8)" ::: "memory");
        asm volatile("s_barrier" ::: "memory");
        COMPUTE(t & 3);
    }
    asm volatile("s_waitcnt vmcnt(4)" ::: "memory");
    asm volatile("s_barrier" ::: "memory");
    COMPUTE((nt - 2) & 3);
    asm volatile("s_waitcnt vmcnt(0)" ::: "memory");
    asm volatile("s_barrier" ::: "memory");
    COMPUTE((nt - 1) & 3);

#pragma unroll
    for (int i = 0; i < 4; ++i)
#pragma unroll
        for (int j = 0; j < 4; ++j) {
            const int col = bn + wc + j * 16 + lo;
            const float bv = bias[col];
#pragma unroll
            for (int r = 0; r < 4; ++r) {
                const int row = bm + wr + i * 16 + hi * 4 + r;
                const float v = acc[i][j][r] + bv;
                if (MODE == 1) {
                    Fo[(size_t)row * N + col] = v;
                } else {
                    const int b = row >> 11, l = row & 2047;
                    const int i3 = col >> 10, h = (col >> 6) & 15, dd = col & 63;
                    const size_t qk = ((size_t)((b * 16 + h) * 2048 + l)) * 64 + dd;
                    if (i3 == 0)
                        Qo[qk] = __float2bfloat16(v * 0.1803368801f);  // /8 * log2(e)
                    else if (i3 == 1)
                        Ko[qk] = __float2bfloat16(v);
                    else
                        Vto[((size_t)((b * 16 + h) * 64 + dd)) * 2048 + l] = __float2bfloat16(v);
                }
            }
        }
}

// ---------------------------------------------------------------- flash attention
// Swapped-operand 32x32, softmax on the (lane, lane^32) pair, exp2 domain,
// defer-rescale THR=8, no P LDS round-trip. Subtile-major LDS layout
// (fragment read = bijection onto 64 contiguous 16B slots).
// Depth-2 prefetch, 4 KV buffers, ONE barrier per tile (distance-3, race-free).
__global__ __launch_bounds__(256) void attn_kernel(
    const bf16* __restrict__ Q, const bf16* __restrict__ Kb, const bf16* __restrict__ Vt,
    bf16* __restrict__ ctx) {
    __shared__ bf16 Ks[4][64 * 64];
    __shared__ bf16 Vs[4][64 * 64];
    const int tid = threadIdx.x, wid = tid >> 6, lane = tid & 63;
    const int lo5 = lane & 31, hi2 = lane >> 5;
    // XCD swizzle: 512 blocks -> chunk 64 = (4 bh) x (16 qtiles) per XCD
    const int bid = blockIdx.x + 16 * blockIdx.y;
    const int sb = (bid & 7) * 64 + (bid >> 3);
    const int bh = sb >> 4;
    const int q0 = (sb & 15) * 128 + wid * 32;
    const bf16* Qh = Q + (size_t)bh * 2048 * 64;
    const char* KhB = (const char*)(Kb + (size_t)bh * 2048 * 64);
    const char* VhB = (const char*)(Vt + (size_t)bh * 64 * 2048);

    // Q B-fragments: lane holds Q[q0+lo5][c*16 + hi2*8 + j]
    bf16x8_t qf[4];
#pragma unroll
    for (int c = 0; c < 4; ++c)
        qf[c] = *(const bf16x8_t*)((const char*)(Qh + (size_t)(q0 + lo5) * 64) + c * 32 + hi2 * 16);
#pragma unroll
    for (int c = 0; c < 4; ++c) asm volatile("" ::"v"(qf[c]));

    // staging source offsets (per-lane, loop-invariant)
    int sK[2], sV[2];
#pragma unroll
    for (int c2 = 0; c2 < 2; ++c2) {
        const int g = wid * 2 + c2;
        const int rowsel = (g & 1) * 32 + (lane >> 1);
        sK[c2] = rowsel * 128 + (g >> 1) * 32 + (lane & 1) * 16;
        sV[c2] = rowsel * 4096 + (g >> 1) * 32 + (lane & 1) * 16;
    }
    const int rdO = lo5 * 32 + hi2 * 16;  // fragment read: lane -> 16B slot bijection

    f32x16_t O0 = {}, O1 = {};
    float m = -1e30f, l = 0.f;

    auto STAGE = [&](int buf, int t) {
#pragma unroll
        for (int c2 = 0; c2 < 2; ++c2) {
            const int g = wid * 2 + c2;
            glds16(KhB + t * 8192 + sK[c2], (char*)&Ks[0][0] + buf * 8192 + g * 1024);
            glds16(VhB + t * 128 + sV[c2], (char*)&Vs[0][0] + buf * 8192 + g * 1024);
        }
    };

    auto TILE = [&](int buf) {
        const char* kb = (const char*)&Ks[0][0] + buf * 8192 + rdO;
        const char* vb = (const char*)&Vs[0][0] + buf * 8192 + rdO;

        // S^T = K . Q  (64 keys x 32 q)
        f32x16_t S0 = {}, S1 = {};
        __builtin_amdgcn_s_setprio(1);
#pragma unroll
        for (int c = 0; c < 4; ++c) {
            bf16x8_t kf0 = *(const bf16x8_t*)(kb + c * 2048);
            bf16x8_t kf1 = *(const bf16x8_t*)(kb + c * 2048 + 1024);
            S0 = MFMA32(kf0, qf[c], S0);
            S1 = MFMA32(kf1, qf[c], S1);
        }
        __builtin_amdgcn_s_setprio(0);

        // online softmax (exp2 domain); keys split across (lane, lane^32)
        float p0 = max3f(S0[0], S0[1], S0[2]);
        float p1 = max3f(S0[8], S0[9], S0[10]);
        float p2 = max3f(S1[0], S1[1], S1[2]);
        float p3 = max3f(S1[8], S1[9], S1[10]);
        p0 = max3f(p0, S0[3], S0[4]);
        p1 = max3f(p1, S0[11], S0[12]);
        p2 = max3f(p2, S1[3], S1[4]);
        p3 = max3f(p3, S1[11], S1[12]);
        p0 = max3f(p0, S0[5], S0[6]);
        p1 = max3f(p1, S0[13], S0[14]);
        p2 = max3f(p2, S1[5], S1[6]);
        p3 = max3f(p3, S1[13], S1[14]);
        p0 = max3f(p0, S0[7], p1);
        p2 = max3f(p2, S1[7], p3);
        float tmax = max3f(p0, S0[15], fmaxf(p2, S1[15]));
        tmax = fmaxf(tmax, __shfl_xor(tmax, 32));  // R4-verified pair combine

        if (__any(tmax > m + 8.f)) {  // defer-rescale (T13)
            const float mn = fmaxf(m, tmax);
            const float sc = __builtin_exp2f(m - mn);
            m = mn;
            l *= sc;
#pragma unroll
            for (int r = 0; r < 16; ++r) {
                O0[r] *= sc;
                O1[r] *= sc;
            }
        }

        float a0 = 0.f, a1 = 0.f, a2 = 0.f, a3 = 0.f;
#pragma unroll
        for (int r = 0; r < 8; ++r) {
            S0[r] = __builtin_exp2f(S0[r] - m);
            a0 += S0[r];
            S0[8 + r] = __builtin_exp2f(S0[8 + r] - m);
            a1 += S0[8 + r];
            S1[r] = __builtin_exp2f(S1[r] - m);
            a2 += S1[r];
            S1[8 + r] = __builtin_exp2f(S1[8 + r] - m);
            a3 += S1[8 + r];
        }
        float rs = (a0 + a1) + (a2 + a3);
        rs += __shfl_xor(rs, 32);  // R4-verified pair combine
        l += rs;

        // pack P^T fragments: 16 packs + 8 permlane32_swap, no LDS
        unsigned w[16];
#pragma unroll
        for (int i = 0; i < 8; ++i) {
            w[i] = pkbf16(S0[2 * i], S0[2 * i + 1]);
            w[8 + i] = pkbf16(S1[2 * i], S1[2 * i + 1]);
        }
        perm32swap(w[0], w[2]);
        perm32swap(w[1], w[3]);
        perm32swap(w[4], w[6]);
        perm32swap(w[5], w[7]);
        perm32swap(w[8], w[10]);
        perm32swap(w[9], w[11]);
        perm32swap(w[12], w[14]);
        perm32swap(w[13], w[15]);

        // O^T += V^T . P^T
        __builtin_amdgcn_s_setprio(1);
#pragma unroll
        for (int c = 0; c < 4; ++c) {
            union { unsigned u[4]; bf16x8_t v; } pf;
            pf.u[0] = w[4 * c];
            pf.u[1] = w[4 * c + 1];
            pf.u[2] = w[4 * c + 2];
            pf.u[3] = w[4 * c + 3];
            bf16x8_t vf0 = *(const bf16x8_t*)(vb + c * 2048);
            bf16x8_t vf1 = *(const bf16x8_t*)(vb + c * 2048 + 1024);
            O0 = MFMA32(vf0, pf.v, O0);
            O1 = MFMA32(vf1, pf.v, O1);
        }
        __builtin_amdgcn_s_setprio(0);
    };

    STAGE(0, 0);
    STAGE(1, 1);
    for (int t = 0; t < 30; ++t) {
        STAGE((t + 2) & 3, t + 2);
        asm volatile("s_waitcnt vmcnt(8)" ::: "memory");
        asm volatile("s_barrier" ::: "memory");
        TILE(t & 3);
    }
    asm volatile("s_waitcnt vmcnt(4)" ::: "memory");
    asm volatile("s_barrier" ::: "memory");
    TILE(2);
    asm volatile("s_waitcnt vmcnt(0)" ::: "memory");
    asm volatile("s_barrier" ::: "memory");
    TILE(3);

    // epilogue: lane-scalar 1/l (identical across the lane pair); 8B vector stores
    const float inv = 1.f / l;
    const int b = bh >> 4, h = bh & 15;
    bf16* cp = ctx + ((size_t)(b * 2048 + q0 + lo5)) * 1024 + h * 64 + hi2 * 4;
#pragma unroll
    for (int db = 0; db < 2; ++db) {
#pragma unroll
        for (int g = 0; g < 4; ++g) {
            union { bf16 h4[4]; unsigned long long u; } o;
#pragma unroll
            for (int r = 0; r < 4; ++r) {
                const float v = (db ? O1[g * 4 + r] : O0[g * 4 + r]) * inv;
                o.h4[r] = __float2bfloat16(v);
            }
            *reinterpret_cast<unsigned long long*>(cp + db * 32 + g * 8) = o.u;
        }
    }
}

// ---------------------------------------------------------------- launch
extern "C" void kernel_launch(void* const* d_in, const int* in_sizes, int n_in,
                              void* d_out, int out_size, void* d_ws, size_t ws_size,
                              hipStream_t stream) {
    const float* x = (const float*)d_in[0];
    const float* Wqkv = (const float*)d_in[2];
    const float* bqkv = (const float*)d_in[3];
    const float* Wout = (const float*)d_in[4];
    const float* bout = (const float*)d_in[5];
    float* out = (float*)d_out;

    char* ws = (char*)d_ws;
    bf16* x_bf = (bf16*)(ws);                    // 8MB; later reused as ctx
    bf16* Wqkv_t = (bf16*)(ws + (8ull << 20));   // 6MB  [3072][1024]
    bf16* Wout_t = (bf16*)(ws + (14ull << 20));  // 2MB  [1024][1024]
    bf16* Qb = (bf16*)(ws + (16ull << 20));      // 8MB  [32][2048][64]
    bf16* Kb = (bf16*)(ws + (24ull << 20));      // 8MB  [32][2048][64]
    bf16* Vtb = (bf16*)(ws + (32ull << 20));     // 8MB  [32][64][2048]

    cvt_f32_bf16<<<4096, 256, 0, stream>>>(x, x_bf, 4194304 / 4);
    transpose_cvt<<<dim3(96, 32), dim3(32, 8), 0, stream>>>(Wqkv, Wqkv_t, 1024, 3072);
    transpose_cvt<<<dim3(32, 32), dim3(32, 8), 0, stream>>>(Wout, Wout_t, 1024, 1024);

    gemm_kernel<0><<<dim3(32, 24), 256, 0, stream>>>(x_bf, Wqkv_t, bqkv, Qb, Kb, Vtb, nullptr,
                                                     3072, 1024);
    attn_kernel<<<dim3(16, 32), 256, 0, stream>>>(Qb, Kb, Vtb, x_bf /*ctx alias*/);
    gemm_kernel<1><<<dim3(32, 8), 256, 0, stream>>>(x_bf, Wout_t, bout, nullptr, nullptr, nullptr,
                                                    out, 1024, 1024);
}

// Round 9
// 141.692 us; speedup vs baseline: 1.1468x; 1.1468x over previous
//
#include <hip/hip_runtime.h>
#include <hip/hip_bf16.h>

typedef __hip_bfloat16 bf16;
typedef __bf16 bf16x8_t __attribute__((ext_vector_type(8)));
typedef float f32x4_t __attribute__((ext_vector_type(4)));
typedef float f32x16_t __attribute__((ext_vector_type(16)));

#define MFMA16(a, b, c) __builtin_amdgcn_mfma_f32_16x16x32_bf16(a, b, c, 0, 0, 0)
#define MFMA32(a, b, c) __builtin_amdgcn_mfma_f32_32x32x16_bf16(a, b, c, 0, 0, 0)

// global -> LDS direct copy, 16B per lane. LDS dest = wave-uniform chunk base
// (HW adds lane*16); global src is per-lane (so we pre-permute the source).
__device__ __forceinline__ void glds16(const void* g, void* l) {
    auto gp = (const __attribute__((address_space(1))) unsigned int*)(unsigned long long)(g);
    auto lp = (__attribute__((address_space(3))) unsigned int*)(unsigned int)(unsigned long long)(l);
    __builtin_amdgcn_global_load_lds(gp, lp, 16, 0, 0);
}

// R4-verified pack: lo16 = bf16(a), hi16 = bf16(b)
__device__ __forceinline__ unsigned pkbf16(float a, float b) {
    union { bf16 h; unsigned short u; } x, y;
    x.h = __float2bfloat16(a);
    y.h = __float2bfloat16(b);
    return ((unsigned)y.u << 16) | x.u;
}

// v_permlane32_swap_b32: a' = [a.lo32 | b.lo32], b' = [a.hi32 | b.hi32].
// PROVEN SAFE only with operands produced several instructions upstream
// (R3/R4/R7). Do NOT feed it a VGPR written in the immediately preceding
// cycle: CDNA4 permlane RAW hazard (R5/R6/R8 failures, ~0.06-0.08 absmax).
__device__ __forceinline__ void perm32swap(unsigned& a, unsigned& b) {
    asm volatile("v_permlane32_swap_b32 %0, %1" : "+v"(a), "+v"(b));
}

__device__ __forceinline__ float max3f(float a, float b, float c) {
    return fmaxf(fmaxf(a, b), c);  // clang fuses to v_max3_f32
}

// ---------------------------------------------------------------- conversions
__global__ void cvt_f32_bf16(const float* __restrict__ in, bf16* __restrict__ out, int n4) {
    int i = blockIdx.x * blockDim.x + threadIdx.x;
    if (i >= n4) return;
    const float4 v = reinterpret_cast<const float4*>(in)[i];
    bf16 o[4] = {__float2bfloat16(v.x), __float2bfloat16(v.y),
                 __float2bfloat16(v.z), __float2bfloat16(v.w)};
    *reinterpret_cast<ulonglong1*>(out + i * 4) = *reinterpret_cast<ulonglong1*>(o);
}

// in [R][C] f32  ->  out [C][R] bf16   (block (32,8), tile 32x32)
__global__ void transpose_cvt(const float* __restrict__ in, bf16* __restrict__ out, int R, int C) {
    __shared__ bf16 tile[32][33];
    const int c0 = blockIdx.x * 32, r0 = blockIdx.y * 32;
    const int tx = threadIdx.x, ty = threadIdx.y;
#pragma unroll
    for (int i = 0; i < 4; ++i) {
        int r = r0 + ty + i * 8;
        tile[ty + i * 8][tx] = __float2bfloat16(in[(size_t)r * C + c0 + tx]);
    }
    __syncthreads();
#pragma unroll
    for (int i = 0; i < 4; ++i) {
        int c = c0 + ty + i * 8;
        out[(size_t)c * R + r0 + tx] = tile[tx][ty + i * 8];
    }
}

// ---------------------------------------------------------------- GEMM
// C[M,N] = A[M,K] @ Bt[N,K]^T + bias.  BM=BN=128, BK=32, 256 thr (4 waves 2x2).
// FOUR LDS buffers, prefetch depth 2, ONE barrier per K-step (R7-proven).
// MODE 0: QKV epilogue -> Q[B,H,L,64] (x 0.125*log2e), K, Vt (packed 8B stores).
// MODE 1: f32 out + bias
template <int MODE>
__global__ __launch_bounds__(256) void gemm_kernel(
    const bf16* __restrict__ A, const bf16* __restrict__ Bt, const float* __restrict__ bias,
    bf16* __restrict__ Qo, bf16* __restrict__ Ko, bf16* __restrict__ Vto,
    float* __restrict__ Fo, int N, int K) {
    __shared__ bf16 As[4][128 * 32];
    __shared__ bf16 Bs[4][128 * 32];
    const int tid = threadIdx.x, wid = tid >> 6, lane = tid & 63;
    const int lo = lane & 15, hi = lane >> 4;
    const int nbx = gridDim.x;
    const int bid = blockIdx.x + nbx * blockIdx.y;
    const int chunk = (nbx * gridDim.y) >> 3;
    const int sb = (bid & 7) * chunk + (bid >> 3);
    const int bm = (sb % nbx) * 128, bn = (sb / nbx) * 128;
    const int wr = (wid >> 1) * 64, wc = (wid & 1) * 64;

    f32x4_t acc[4][4];
#pragma unroll
    for (int i = 0; i < 4; ++i)
#pragma unroll
        for (int j = 0; j < 4; ++j) acc[i][j] = (f32x4_t){0.f, 0.f, 0.f, 0.f};

    const int g0 = wid * 2, g1 = wid * 2 + 1;
    const int r0 = (g0 * 1024 + lane * 16) >> 6, k0off = ((g0 * 1024 + lane * 16) & 63) >> 1;
    const int r1 = (g1 * 1024 + lane * 16) >> 6, k1off = ((g1 * 1024 + lane * 16) & 63) >> 1;

    auto STAGE = [&](int buf, int t) {
        const int kk = t * 32;
        glds16(A + (size_t)(bm + r0) * K + kk + k0off, (char*)&As[0][0] + buf * 8192 + g0 * 1024);
        glds16(Bt + (size_t)(bn + r0) * K + kk + k0off, (char*)&Bs[0][0] + buf * 8192 + g0 * 1024);
        glds16(A + (size_t)(bm + r1) * K + kk + k1off, (char*)&As[0][0] + buf * 8192 + g1 * 1024);
        glds16(Bt + (size_t)(bn + r1) * K + kk + k1off, (char*)&Bs[0][0] + buf * 8192 + g1 * 1024);
    };

    auto COMPUTE = [&](int buf) {
        const char* ab = (const char*)&As[0][0] + buf * 8192;
        const char* bb = (const char*)&Bs[0][0] + buf * 8192;
        bf16x8_t af[4], bfv[4];
#pragma unroll
        for (int i = 0; i < 4; ++i)
            af[i] = *(const bf16x8_t*)(ab + (wr + i * 16 + lo) * 64 + hi * 16);
#pragma unroll
        for (int j = 0; j < 4; ++j)
            bfv[j] = *(const bf16x8_t*)(bb + (wc + j * 16 + lo) * 64 + hi * 16);
        __builtin_amdgcn_s_setprio(1);
#pragma unroll
        for (int i = 0; i < 4; ++i)
#pragma unroll
            for (int j = 0; j < 4; ++j) acc[i][j] = MFMA16(af[i], bfv[j], acc[i][j]);
        __builtin_amdgcn_s_setprio(0);
    };

    const int nt = K >> 5;  // 32
    STAGE(0, 0);
    STAGE(1, 1);
    for (int t = 0; t < nt - 2; ++t) {
        STAGE((t + 2) & 3, t + 2);
        asm volatile("s_waitcnt vmcnt(8)" ::: "memory");
        asm volatile("s_barrier" ::: "memory");
        COMPUTE(t & 3);
    }
    asm volatile("s_waitcnt vmcnt(4)" ::: "memory");
    asm volatile("s_barrier" ::: "memory");
    COMPUTE((nt - 2) & 3);
    asm volatile("s_waitcnt vmcnt(0)" ::: "memory");
    asm volatile("s_barrier" ::: "memory");
    COMPUTE((nt - 1) & 3);

#pragma unroll
    for (int i = 0; i < 4; ++i)
#pragma unroll
        for (int j = 0; j < 4; ++j) {
            const int col = bn + wc + j * 16 + lo;
            const float bv = bias[col];
            if (MODE == 1) {
#pragma unroll
                for (int r = 0; r < 4; ++r) {
                    const int row = bm + wr + i * 16 + hi * 4 + r;
                    Fo[(size_t)row * N + col] = acc[i][j][r] + bv;
                }
            } else {
                const int row0 = bm + wr + i * 16 + hi * 4;
                const int b = row0 >> 11, l0 = row0 & 2047;
                const int i3 = col >> 10, h = (col >> 6) & 15, dd = col & 63;
                if (i3 == 2) {
                    union { bf16 h4[4]; unsigned long long u; } o;
#pragma unroll
                    for (int r = 0; r < 4; ++r) o.h4[r] = __float2bfloat16(acc[i][j][r] + bv);
                    *reinterpret_cast<unsigned long long*>(
                        Vto + ((size_t)((b * 16 + h) * 64 + dd)) * 2048 + l0) = o.u;
                } else {
#pragma unroll
                    for (int r = 0; r < 4; ++r) {
                        const float v = acc[i][j][r] + bv;
                        const size_t qk = ((size_t)((b * 16 + h) * 2048 + l0 + r)) * 64 + dd;
                        if (i3 == 0)
                            Qo[qk] = __float2bfloat16(v * 0.1803368801f);  // /8 * log2(e)
                        else
                            Ko[qk] = __float2bfloat16(v);
                    }
                }
            }
        }
}

// ---------------------------------------------------------------- flash attention
// 512 threads = 8 waves: group 0 (waves 0-3) keys [0,1024), group 1 keys
// [1024,2048); both cover the same 128 q-rows (wave wq owns 32). KVBLK=32,
// 4-buffer ring per group, depth-2 prefetch, ONE barrier per tile.
// Swapped-operand 32x32, pair softmax via __shfl_xor(32) (R4/R7-proven),
// exp2 domain, defer-rescale. Final in-LDS flash combine of the two halves.
// LDS 64KB: grp ring at grp*32768 + buf*8192 (K 4KB @ +0, V 4KB @ +4096).
__global__ __launch_bounds__(512, 4) void attn_kernel(
    const bf16* __restrict__ Q, const bf16* __restrict__ Kb, const bf16* __restrict__ Vt,
    bf16* __restrict__ ctx) {
    __shared__ char lds[65536];
    const int tid = threadIdx.x, wid = tid >> 6, lane = tid & 63;
    const int grp = wid >> 2, wq = wid & 3;
    const int lo5 = lane & 31, hi2 = lane >> 5;
    const int bid = blockIdx.x + 16 * blockIdx.y;
    const int sb = (bid & 7) * 64 + (bid >> 3);
    const int bh = sb >> 4;
    const int q0 = (sb & 15) * 128 + wq * 32;
    const bf16* Qh = Q + (size_t)bh * 2048 * 64;
    const char* KhB = (const char*)(Kb + (size_t)bh * 2048 * 64);
    const char* VhB = (const char*)(Vt + (size_t)bh * 64 * 2048);
    char* const ring = lds + grp * 32768;

    bf16x8_t qf[4];
#pragma unroll
    for (int c = 0; c < 4; ++c)
        qf[c] = *(const bf16x8_t*)((const char*)(Qh + (size_t)(q0 + lo5) * 64) + c * 32 + hi2 * 16);
#pragma unroll
    for (int c = 0; c < 4; ++c) asm volatile("" ::"v"(qf[c]));

    // staging sources: wave wq stages K-chunk wq ([32 key][16 d] @ d-base wq*16)
    // and V-chunk wq (key sub cks=wq>>1, d-half dh=wq&1)
    const int sKoff = (lane >> 1) * 128 + wq * 32 + (lane & 1) * 16;
    const int cks = wq >> 1, dh = wq & 1;
    const int sVrow = dh * 32 + (lane >> 1);
    const int sVkey = cks * 16 + (lane & 1) * 8;

    const int rdO = lo5 * 32 + hi2 * 16;

    f32x16_t O0 = {}, O1 = {};
    float m = -1e30f, l = 0.f;

    auto STAGE = [&](int buf, int t) {
        const int keybase = grp * 1024 + t * 32;
        glds16(KhB + (size_t)keybase * 128 + sKoff, ring + buf * 8192 + wq * 1024);
        glds16(VhB + (size_t)sVrow * 4096 + (size_t)(keybase + sVkey) * 2,
               ring + buf * 8192 + 4096 + wq * 1024);
    };

    auto TILE = [&](int buf) {
        const char* kb = ring + buf * 8192 + rdO;
        const char* vb = kb + 4096;

        f32x16_t S = {};
        __builtin_amdgcn_s_setprio(1);
#pragma unroll
        for (int c = 0; c < 4; ++c) {
            bf16x8_t kf = *(const bf16x8_t*)(kb + c * 1024);
            S = MFMA32(kf, qf[c], S);
        }
        __builtin_amdgcn_s_setprio(0);

        float t0 = max3f(S[0], S[1], S[2]);
        float t1 = max3f(S[8], S[9], S[10]);
        t0 = max3f(t0, S[3], S[4]);
        t1 = max3f(t1, S[11], S[12]);
        t0 = max3f(t0, S[5], S[6]);
        t1 = max3f(t1, S[13], S[14]);
        float tmax = fmaxf(max3f(t0, S[7], t1), S[15]);
        tmax = fmaxf(tmax, __shfl_xor(tmax, 32));  // R4/R7-proven pair combine

        if (__any(tmax > m + 8.f)) {
            const float mn = fmaxf(m, tmax);
            const float sc = __builtin_exp2f(m - mn);
            m = mn;
            l *= sc;
#pragma unroll
            for (int r = 0; r < 16; ++r) {
                O0[r] *= sc;
                O1[r] *= sc;
            }
        }

        float a0 = 0.f, a1 = 0.f;
#pragma unroll
        for (int r = 0; r < 8; ++r) {
            S[r] = __builtin_exp2f(S[r] - m);
            a0 += S[r];
            S[8 + r] = __builtin_exp2f(S[8 + r] - m);
            a1 += S[8 + r];
        }
        float rs = a0 + a1;
        rs += __shfl_xor(rs, 32);  // R4/R7-proven pair combine
        l += rs;

        unsigned w[8];
#pragma unroll
        for (int i = 0; i < 8; ++i) w[i] = pkbf16(S[2 * i], S[2 * i + 1]);
        perm32swap(w[0], w[2]);
        perm32swap(w[1], w[3]);
        perm32swap(w[4], w[6]);
        perm32swap(w[5], w[7]);

        union { unsigned u[4]; bf16x8_t v; } pf0, pf1;
        pf0.u[0] = w[0]; pf0.u[1] = w[1]; pf0.u[2] = w[2]; pf0.u[3] = w[3];
        pf1.u[0] = w[4]; pf1.u[1] = w[5]; pf1.u[2] = w[6]; pf1.u[3] = w[7];
        __builtin_amdgcn_s_setprio(1);
        {
            bf16x8_t v00 = *(const bf16x8_t*)(vb);
            bf16x8_t v10 = *(const bf16x8_t*)(vb + 2048);
            bf16x8_t v01 = *(const bf16x8_t*)(vb + 1024);
            bf16x8_t v11 = *(const bf16x8_t*)(vb + 3072);
            O0 = MFMA32(v00, pf0.v, O0);
            O0 = MFMA32(v10, pf1.v, O0);
            O1 = MFMA32(v01, pf0.v, O1);
            O1 = MFMA32(v11, pf1.v, O1);
        }
        __builtin_amdgcn_s_setprio(0);
    };

    STAGE(0, 0);
    STAGE(1, 1);
    for (int t = 0; t < 30; ++t) {
        STAGE((t + 2) & 3, t + 2);
        asm volatile("s_waitcnt vmcnt(4)" ::: "memory");
        asm volatile("s_barrier" ::: "memory");
        TILE(t & 3);
    }
    asm volatile("s_waitcnt vmcnt(2)" ::: "memory");
    asm volatile("s_barrier" ::: "memory");
    TILE(2);
    asm volatile("s_waitcnt vmcnt(0)" ::: "memory");
    asm volatile("s_barrier" ::: "memory");
    TILE(3);

    // ---- combine the two key-half partials via LDS ----
    __syncthreads();
    if (grp == 1) {
        float* oa = (float*)(lds + wq * 8192);
        float* ml = (float*)(lds + 32768);
#pragma unroll
        for (int r = 0; r < 16; ++r) {
            oa[r * 64 + lane] = O0[r];
            oa[1024 + r * 64 + lane] = O1[r];
        }
        ml[wq * 128 + lane] = m;
        ml[wq * 128 + 64 + lane] = l;
    }
    __syncthreads();
    if (grp == 0) {
        const float* oa = (const float*)(lds + wq * 8192);
        const float* ml = (const float*)(lds + 32768);
        const float mb = ml[wq * 128 + lane];
        const float lb = ml[wq * 128 + 64 + lane];
        const float mN = fmaxf(m, mb);
        const float sA = __builtin_exp2f(m - mN);
        const float sB = __builtin_exp2f(mb - mN);
        const float lt = l * sA + lb * sB;
        const float inv = 1.f / lt;
#pragma unroll
        for (int r = 0; r < 16; ++r) {
            O0[r] = O0[r] * sA + oa[r * 64 + lane] * sB;
            O1[r] = O1[r] * sA + oa[1024 + r * 64 + lane] * sB;
        }
        const int b = bh >> 4, h = bh & 15;
        bf16* cp = ctx + ((size_t)(b * 2048 + q0 + lo5)) * 1024 + h * 64 + hi2 * 4;
#pragma unroll
        for (int db = 0; db < 2; ++db) {
#pragma unroll
            for (int g = 0; g < 4; ++g) {
                union { bf16 h4[4]; unsigned long long u; } o;
#pragma unroll
                for (int r = 0; r < 4; ++r) {
                    const float v = (db ? O1[g * 4 + r] : O0[g * 4 + r]) * inv;
                    o.h4[r] = __float2bfloat16(v);
                }
                *reinterpret_cast<unsigned long long*>(cp + db * 32 + g * 8) = o.u;
            }
        }
    }
}

// ---------------------------------------------------------------- launch
extern "C" void kernel_launch(void* const* d_in, const int* in_sizes, int n_in,
                              void* d_out, int out_size, void* d_ws, size_t ws_size,
                              hipStream_t stream) {
    const float* x = (const float*)d_in[0];
    const float* Wqkv = (const float*)d_in[2];
    const float* bqkv = (const float*)d_in[3];
    const float* Wout = (const float*)d_in[4];
    const float* bout = (const float*)d_in[5];
    float* out = (float*)d_out;

    char* ws = (char*)d_ws;
    bf16* x_bf = (bf16*)(ws);                    // 8MB; later reused as ctx
    bf16* Wqkv_t = (bf16*)(ws + (8ull << 20));   // 6MB  [3072][1024]
    bf16* Wout_t = (bf16*)(ws + (14ull << 20));  // 2MB  [1024][1024]
    bf16* Qb = (bf16*)(ws + (16ull << 20));      // 8MB  [32][2048][64]
    bf16* Kb = (bf16*)(ws + (24ull << 20));      // 8MB  [32][2048][64]
    bf16* Vtb = (bf16*)(ws + (32ull << 20));     // 8MB  [32][64][2048]

    cvt_f32_bf16<<<4096, 256, 0, stream>>>(x, x_bf, 4194304 / 4);
    transpose_cvt<<<dim3(96, 32), dim3(32, 8), 0, stream>>>(Wqkv, Wqkv_t, 1024, 3072);
    transpose_cvt<<<dim3(32, 32), dim3(32, 8), 0, stream>>>(Wout, Wout_t, 1024, 1024);

    gemm_kernel<0><<<dim3(32, 24), 256, 0, stream>>>(x_bf, Wqkv_t, bqkv, Qb, Kb, Vtb, nullptr,
                                                     3072, 1024);
    attn_kernel<<<dim3(16, 32), 512, 0, stream>>>(Qb, Kb, Vtb, x_bf /*ctx alias*/);
    gemm_kernel<1><<<dim3(32, 8), 256, 0, stream>>>(x_bf, Wout_t, bout, nullptr, nullptr, nullptr,
                                                    out, 1024, 1024);
}